// Round 9
// baseline (1910.892 us; speedup 1.0000x reference)
//
#include <hip/hip_runtime.h>
#include <math.h>

#define NODES   325
#define TOPK    8
#define B_SZ    8
#define T_LEN   64
#define EPS     1e-5f
#define NTOK    ((size_t)B_SZ * T_LEN * NODES)   /* 166,400 */

/* ---- LDS layout for opt_mamba R9 (dynamic, floats) ----
   s_h  [64][68]  LN output (read-only after ph1; alive to the end)  4352
   s_xc [64][132] xi -> xc -> y -> u                                  8448
   sW   [4352]    64-row weight chunk; hosts dbl[64][40] in the
                  scan window (sW dead there)                         4352
   total 17152 floats = 68608 B -> probe for 2 blocks/CU
   (bracket: 61.4 KB -> 2 blk [R5 occ 44.8%]; 78.8 KB -> 1 blk [R4])
   Spill-safety: z computed AFTER the scan (no registers alive across
   it) -- R7's spill cause removed. No launch_bounds VGPR cap (R5). */
#define HPAD    68
#define XCPAD   132
#define DBLPAD  40
#define WH      68
#define OFF_H   0
#define OFF_XC  4352
#define OFF_W   12800
#define SMEM_BYTES (17152*4)

__device__ __forceinline__ float waveSum64(float v){
  #pragma unroll
  for(int m=1;m<64;m<<=1) v += __shfl_xor(v, m, 64);
  return v;
}
__device__ __forceinline__ float groupSum16(float v){
  v += __shfl_xor(v, 1, 64);
  v += __shfl_xor(v, 2, 64);
  v += __shfl_xor(v, 4, 64);
  v += __shfl_xor(v, 8, 64);
  return v;
}
__device__ __forceinline__ float dot64(const float* __restrict__ s,
                                       const float* __restrict__ w, float acc){
  #pragma unroll
  for(int q=0;q<64;q++) acc = fmaf(s[q], w[q], acc);
  return acc;
}
__device__ __forceinline__ float4 f4fma(float s, float4 a, float4 acc){
  acc.x = fmaf(s, a.x, acc.x);
  acc.y = fmaf(s, a.y, acc.y);
  acc.z = fmaf(s, a.z, acc.z);
  acc.w = fmaf(s, a.w, acc.w);
  return acc;
}
__device__ __forceinline__ float dp4(float4 a, float4 b, float acc){
  acc = fmaf(a.x, b.x, acc);
  acc = fmaf(a.y, b.y, acc);
  acc = fmaf(a.z, b.z, acc);
  acc = fmaf(a.w, b.w, acc);
  return acc;
}

// ---------------- Mamba R9: chunked LDS weights, 68.6 KB, z-after-scan ----------------
__global__ __launch_bounds__(512)
void opt_mamba(const float* __restrict__ x,
               const float* __restrict__ ln1_g, const float* __restrict__ ln1_b,
               const float* __restrict__ in_w,
               const float* __restrict__ conv_w, const float* __restrict__ conv_b,
               const float* __restrict__ xp_w,
               const float* __restrict__ dt_w, const float* __restrict__ dt_b,
               const float* __restrict__ A_log, const float* __restrict__ Dss,
               const float* __restrict__ out_w,
               float* __restrict__ xT)
{
  extern __shared__ float sm[];
  float* s_h   = sm + OFF_H;
  float* s_xc  = sm + OFF_XC;
  float* sW    = sm + OFF_W;     // weight chunk; aliased as s_dbl in scan window
  float* s_dbl = sW;

  const int bn   = blockIdx.x;
  const int b    = bn / NODES;
  const int n    = bn % NODES;
  const int tid  = threadIdx.x;
  const int lane = tid & 63;
  const int wv   = tid >> 6;

  // chunk GEMM tiling: 4 rows x 2 tokens per thread
  const int r0 = (tid & 15) * 4;     // row-in-chunk r0..r0+3 (0..63)
  const int tA = (tid >> 4) * 2;     // tokens tA, tA+1

  // 64-row chunk matvec from s_h: 4 rows x 2 tokens
  #define MM64(OUT0, OUT1)                                                  \
  {                                                                         \
    OUT0 = make_float4(0.f,0.f,0.f,0.f); OUT1 = OUT0;                       \
    for(int c0=0;c0<64;c0+=4){                                              \
      float4 w0 = *(const float4*)&sW[(c0+0)*WH + r0];                      \
      float4 w1 = *(const float4*)&sW[(c0+1)*WH + r0];                      \
      float4 w2 = *(const float4*)&sW[(c0+2)*WH + r0];                      \
      float4 w3 = *(const float4*)&sW[(c0+3)*WH + r0];                      \
      float4 h0 = *(const float4*)&s_h[(tA+0)*HPAD + c0];                   \
      float4 h1 = *(const float4*)&s_h[(tA+1)*HPAD + c0];                   \
      OUT0 = f4fma(h0.x,w0,OUT0); OUT0 = f4fma(h0.y,w1,OUT0);               \
      OUT0 = f4fma(h0.z,w2,OUT0); OUT0 = f4fma(h0.w,w3,OUT0);               \
      OUT1 = f4fma(h1.x,w0,OUT1); OUT1 = f4fma(h1.y,w1,OUT1);               \
      OUT1 = f4fma(h1.z,w2,OUT1); OUT1 = f4fma(h1.w,w3,OUT1);               \
    }                                                                       \
  }
  // stage in_w rows rbase..rbase+63 transposed: sW[c*WH + r]
  #define STAGE_IN(RBASE)                                                   \
  for(int idx = tid; idx < 4096; idx += 512){                               \
    int r = idx >> 6, c = idx & 63;                                         \
    sW[c*WH + r] = in_w[((RBASE) + r)*64 + c];                              \
  }
  // stage out_w cols cbase..cbase+63: sW[c*WH + j]
  #define STAGE_OUT(CBASE)                                                  \
  for(int idx = tid; idx < 4096; idx += 512){                               \
    int c = idx & 63, j = idx >> 6;                                         \
    sW[c*WH + j] = out_w[j*128 + (CBASE) + c];                              \
  }

  // ---- ph1: stage xi-lo + LayerNorm all 64 tokens -> s_h
  STAGE_IN(0);
  {
    const float g_ln = ln1_g[lane], b_ln = ln1_b[lane];
    #pragma unroll
    for(int i=0;i<8;i++){
      int t = wv*8 + i;
      size_t tok = (size_t)(b*T_LEN + t)*NODES + n;
      float v   = x[tok*64 + lane];
      float m   = waveSum64(v) * (1.f/64.f);
      float c   = v - m;
      float var = waveSum64(c*c) * (1.f/64.f);
      s_h[t*HPAD + lane] = c * rsqrtf(var + EPS) * g_ln + b_ln;
    }
  }
  __syncthreads();

  // ---- ph2: xi rows 0..63 -> s_xc[:, 0:64]
  { float4 a0, a1; MM64(a0, a1);
    *(float4*)&s_xc[(tA+0)*XCPAD + r0] = a0;
    *(float4*)&s_xc[(tA+1)*XCPAD + r0] = a1; }
  __syncthreads();
  STAGE_IN(64);
  __syncthreads();

  // ---- ph3: xi rows 64..127 -> s_xc[:, 64:128]
  { float4 a0, a1; MM64(a0, a1);
    *(float4*)&s_xc[(tA+0)*XCPAD + 64 + r0] = a0;
    *(float4*)&s_xc[(tA+1)*XCPAD + 64 + r0] = a1; }
  __syncthreads();

  // ---- ph4: causal conv (window 4) + silu, 4 token-quarters (R3-proven)
  {
    const int dd = tid & 127, tg = tid >> 7;
    float p3 = 0.f, p2 = 0.f, p1 = 0.f;
    if(tg){
      int tq = tg*16;
      p3 = s_xc[(tq-3)*XCPAD + dd];
      p2 = s_xc[(tq-2)*XCPAD + dd];
      p1 = s_xc[(tq-1)*XCPAD + dd];
    }
    __syncthreads();
    const float cw0 = conv_w[dd*4+0], cw1 = conv_w[dd*4+1];
    const float cw2 = conv_w[dd*4+2], cw3 = conv_w[dd*4+3];
    const float cb  = conv_b[dd];
    for(int t=tg*16; t<tg*16+16; t++){
      float xi = s_xc[t*XCPAD + dd];
      float v  = cb + cw0*p3 + cw1*p2 + cw2*p1 + cw3*xi;
      p3 = p2; p2 = p1; p1 = xi;
      s_xc[t*XCPAD + dd] = v / (1.f + __expf(-v));
    }
  }
  __syncthreads();

  // ---- ph5: dbl = xc @ x_proj.T -> s_dbl (in sW region; sW dead here)
  {
    const int td2 = tid & 63, rg = tid >> 6;
    const int base = rg*5;
    float dacc[5];
    #pragma unroll
    for(int i=0;i<5;i++) dacc[i] = 0.f;
    for(int c0=0;c0<128;c0+=4){
      float4 xc4 = *(const float4*)&s_xc[td2*XCPAD + c0];
      #pragma unroll
      for(int i=0;i<5;i++){
        if(base+i < 36){
          float4 w4 = *(const float4*)&xp_w[(base+i)*128 + c0];
          dacc[i] = dp4(xc4, w4, dacc[i]);
        }
      }
    }
    #pragma unroll
    for(int i=0;i<5;i++)
      if(base+i < 36) s_dbl[td2*DBLPAD + base + i] = dacc[i];
  }
  __syncthreads();

  // ---- ph6: selective scan, all 512 threads (d = tid>>2, s-quartet = tid&3)
  {
    const int d  = tid >> 2;
    const int sq = tid & 3;
    float A_d[4], hs[4];
    #pragma unroll
    for(int i=0;i<4;i++){ A_d[i] = -__expf(A_log[d*16 + sq*4 + i]); hs[i] = 0.f; }
    const float dtw0 = dt_w[d*4+0], dtw1 = dt_w[d*4+1];
    const float dtw2 = dt_w[d*4+2], dtw3 = dt_w[d*4+3];
    const float dtb  = dt_b[d], Dd = Dss[d];
    for(int t=0;t<T_LEN;t++){
      const float* db = &s_dbl[t*DBLPAD];
      float4 dt4 = *(const float4*)db;
      float dtv = dtb;
      dtv = fmaf(dt4.x, dtw0, dtv);
      dtv = fmaf(dt4.y, dtw1, dtv);
      dtv = fmaf(dt4.z, dtw2, dtv);
      dtv = fmaf(dt4.w, dtw3, dtv);
      dtv = fmaxf(dtv, 0.f) + log1pf(__expf(-fabsf(dtv)));   // softplus
      float xc = s_xc[t*XCPAD + d];
      float dx = dtv * xc;
      float4 Bv = *(const float4*)&db[4  + sq*4];
      float4 Cv = *(const float4*)&db[20 + sq*4];
      float yp = 0.f;
      hs[0] = fmaf(dx, Bv.x, hs[0]*__expf(dtv*A_d[0])); yp = fmaf(hs[0], Cv.x, yp);
      hs[1] = fmaf(dx, Bv.y, hs[1]*__expf(dtv*A_d[1])); yp = fmaf(hs[1], Cv.y, yp);
      hs[2] = fmaf(dx, Bv.z, hs[2]*__expf(dtv*A_d[2])); yp = fmaf(hs[2], Cv.z, yp);
      hs[3] = fmaf(dx, Bv.w, hs[3]*__expf(dtv*A_d[3])); yp = fmaf(hs[3], Cv.w, yp);
      yp += __shfl_xor(yp, 1, 64);
      yp += __shfl_xor(yp, 2, 64);
      if(sq == 0) s_xc[t*XCPAD + d] = yp + Dd*xc;
    }
  }
  __syncthreads();

  // ---- ph7: z-lo (in_w rows 128..191) -> u = y * silu(z) for d 0..63
  STAGE_IN(128);
  __syncthreads();
  {
    float4 z0, z1; MM64(z0, z1);
    float4 y0 = *(const float4*)&s_xc[(tA+0)*XCPAD + r0];
    float4 y1 = *(const float4*)&s_xc[(tA+1)*XCPAD + r0];
    float4 u0, u1;
    u0.x = y0.x*(z0.x/(1.f+__expf(-z0.x))); u0.y = y0.y*(z0.y/(1.f+__expf(-z0.y)));
    u0.z = y0.z*(z0.z/(1.f+__expf(-z0.z))); u0.w = y0.w*(z0.w/(1.f+__expf(-z0.w)));
    u1.x = y1.x*(z1.x/(1.f+__expf(-z1.x))); u1.y = y1.y*(z1.y/(1.f+__expf(-z1.y)));
    u1.z = y1.z*(z1.z/(1.f+__expf(-z1.z))); u1.w = y1.w*(z1.w/(1.f+__expf(-z1.w)));
    *(float4*)&s_xc[(tA+0)*XCPAD + r0] = u0;
    *(float4*)&s_xc[(tA+1)*XCPAD + r0] = u1;
  }
  __syncthreads();

  // ---- ph8: z-hi (in_w rows 192..255) -> u for d 64..127
  STAGE_IN(192);
  __syncthreads();
  {
    float4 z0, z1; MM64(z0, z1);
    float4 y0 = *(const float4*)&s_xc[(tA+0)*XCPAD + 64 + r0];
    float4 y1 = *(const float4*)&s_xc[(tA+1)*XCPAD + 64 + r0];
    float4 u0, u1;
    u0.x = y0.x*(z0.x/(1.f+__expf(-z0.x))); u0.y = y0.y*(z0.y/(1.f+__expf(-z0.y)));
    u0.z = y0.z*(z0.z/(1.f+__expf(-z0.z))); u0.w = y0.w*(z0.w/(1.f+__expf(-z0.w)));
    u1.x = y1.x*(z1.x/(1.f+__expf(-z1.x))); u1.y = y1.y*(z1.y/(1.f+__expf(-z1.y)));
    u1.z = y1.z*(z1.z/(1.f+__expf(-z1.z))); u1.w = y1.w*(z1.w/(1.f+__expf(-z1.w)));
    *(float4*)&s_xc[(tA+0)*XCPAD + 64 + r0] = u0;
    *(float4*)&s_xc[(tA+1)*XCPAD + 64 + r0] = u1;
  }
  __syncthreads();

  // ---- ph9: out = u @ out_w.T in 2 col-chunks + residual -> xT
  {
    STAGE_OUT(0);
    __syncthreads();
    float4 a0 = make_float4(0.f,0.f,0.f,0.f), a1 = a0;
    for(int c0=0;c0<64;c0+=4){
      float4 w0 = *(const float4*)&sW[(c0+0)*WH + r0];
      float4 w1 = *(const float4*)&sW[(c0+1)*WH + r0];
      float4 w2 = *(const float4*)&sW[(c0+2)*WH + r0];
      float4 w3 = *(const float4*)&sW[(c0+3)*WH + r0];
      float4 u0 = *(const float4*)&s_xc[(tA+0)*XCPAD + c0];
      float4 u1 = *(const float4*)&s_xc[(tA+1)*XCPAD + c0];
      a0 = f4fma(u0.x,w0,a0); a0 = f4fma(u0.y,w1,a0);
      a0 = f4fma(u0.z,w2,a0); a0 = f4fma(u0.w,w3,a0);
      a1 = f4fma(u1.x,w0,a1); a1 = f4fma(u1.y,w1,a1);
      a1 = f4fma(u1.z,w2,a1); a1 = f4fma(u1.w,w3,a1);
    }
    __syncthreads();
    STAGE_OUT(64);
    __syncthreads();
    for(int c0=0;c0<64;c0+=4){
      float4 w0 = *(const float4*)&sW[(c0+0)*WH + r0];
      float4 w1 = *(const float4*)&sW[(c0+1)*WH + r0];
      float4 w2 = *(const float4*)&sW[(c0+2)*WH + r0];
      float4 w3 = *(const float4*)&sW[(c0+3)*WH + r0];
      float4 u0 = *(const float4*)&s_xc[(tA+0)*XCPAD + 64 + c0];
      float4 u1 = *(const float4*)&s_xc[(tA+1)*XCPAD + 64 + c0];
      a0 = f4fma(u0.x,w0,a0); a0 = f4fma(u0.y,w1,a0);
      a0 = f4fma(u0.z,w2,a0); a0 = f4fma(u0.w,w3,a0);
      a1 = f4fma(u1.x,w0,a1); a1 = f4fma(u1.y,w1,a1);
      a1 = f4fma(u1.z,w2,a1); a1 = f4fma(u1.w,w3,a1);
    }
    size_t tok0 = (size_t)(b*T_LEN + tA+0)*NODES + n;
    size_t tok1 = (size_t)(b*T_LEN + tA+1)*NODES + n;
    float4 xv0 = *(const float4*)&x[tok0*64 + r0];
    float4 xv1 = *(const float4*)&x[tok1*64 + r0];
    float4 o0, o1;
    o0.x = xv0.x + a0.x; o0.y = xv0.y + a0.y; o0.z = xv0.z + a0.z; o0.w = xv0.w + a0.w;
    o1.x = xv1.x + a1.x; o1.y = xv1.y + a1.y; o1.z = xv1.z + a1.z; o1.w = xv1.w + a1.w;
    *(float4*)&xT[tok0*64 + r0] = o0;
    *(float4*)&xT[tok1*64 + r0] = o1;
  }
  #undef MM64
  #undef STAGE_IN
  #undef STAGE_OUT
}

// ---------------- K/V + gate projection (R8-validated, unchanged) ----------------
__global__ __launch_bounds__(256)
void opt_proj(const float* __restrict__ xT,
              const float* __restrict__ k_w, const float* __restrict__ k_b,
              const float* __restrict__ v_w, const float* __restrict__ v_b,
              const float* __restrict__ g1_w, const float* __restrict__ g1_b,
              const float* __restrict__ g2_w, const float* __restrict__ g2_b,
              float* __restrict__ Kb, float* __restrict__ Vb,
              float* __restrict__ gate)
{
  __shared__ float s_x[64*68];
  const int tid = threadIdx.x;
  const size_t tb = (size_t)blockIdx.x * 64;

  for(int i = tid; i < 64*64; i += 256){
    int t = i >> 6, c = i & 63;
    s_x[t*68 + c] = xT[(tb + t)*64 + c];
  }
  __syncthreads();

  const int r0 = (tid & 15) * 4;
  const int t0 = (tid >> 4) * 4;

  {
    float4 b4 = *(const float4*)&k_b[r0];
    float4 acc[4];
    #pragma unroll
    for(int tt=0;tt<4;tt++) acc[tt] = b4;
    for(int c0=0;c0<64;c0+=4){
      float4 w0 = *(const float4*)&k_w[(r0+0)*64 + c0];
      float4 w1 = *(const float4*)&k_w[(r0+1)*64 + c0];
      float4 w2 = *(const float4*)&k_w[(r0+2)*64 + c0];
      float4 w3 = *(const float4*)&k_w[(r0+3)*64 + c0];
      #pragma unroll
      for(int tt=0;tt<4;tt++){
        float4 x4 = *(const float4*)&s_x[(t0+tt)*68 + c0];
        acc[tt].x = dp4(x4, w0, acc[tt].x);
        acc[tt].y = dp4(x4, w1, acc[tt].y);
        acc[tt].z = dp4(x4, w2, acc[tt].z);
        acc[tt].w = dp4(x4, w3, acc[tt].w);
      }
    }
    #pragma unroll
    for(int tt=0;tt<4;tt++)
      *(float4*)&Kb[(tb + t0 + tt)*64 + r0] = acc[tt];
  }

  {
    float4 b4 = *(const float4*)&v_b[r0];
    float4 acc[4];
    #pragma unroll
    for(int tt=0;tt<4;tt++) acc[tt] = b4;
    for(int c0=0;c0<64;c0+=4){
      float4 w0 = *(const float4*)&v_w[(r0+0)*64 + c0];
      float4 w1 = *(const float4*)&v_w[(r0+1)*64 + c0];
      float4 w2 = *(const float4*)&v_w[(r0+2)*64 + c0];
      float4 w3 = *(const float4*)&v_w[(r0+3)*64 + c0];
      #pragma unroll
      for(int tt=0;tt<4;tt++){
        float4 x4 = *(const float4*)&s_x[(t0+tt)*68 + c0];
        acc[tt].x = dp4(x4, w0, acc[tt].x);
        acc[tt].y = dp4(x4, w1, acc[tt].y);
        acc[tt].z = dp4(x4, w2, acc[tt].z);
        acc[tt].w = dp4(x4, w3, acc[tt].w);
      }
    }
    #pragma unroll
    for(int tt=0;tt<4;tt++)
      *(float4*)&Vb[(tb + t0 + tt)*64 + r0] = acc[tt];
  }

  {
    const int td = tid >> 2;
    const int sr = (tid & 3) * 4;
    float partial = 0.f;
    #pragma unroll
    for(int i=0;i<4;i++){
      int r = sr + i;
      float u = dot64(&s_x[td*68], g1_w + r*64, g1_b[r]);
      u = 0.5f * u * (1.f + erff(u * 0.70710678118654752f));
      partial = fmaf(u, g2_w[r], partial);
    }
    partial += __shfl_xor(partial, 1, 64);
    partial += __shfl_xor(partial, 2, 64);
    if((tid & 3) == 0)
      gate[tb + td] = 1.f / (1.f + __expf(-(partial + g2_b[0])));
  }
}

// ---------------- R9 tile attention (validated, unchanged) ----------------
__global__ __launch_bounds__(256)
void opt_attn3(const float* __restrict__ xT,
               const float* __restrict__ Kb, const float* __restrict__ Vb,
               const float* __restrict__ gate, const int* __restrict__ nbr,
               const float* __restrict__ q_w, const float* __restrict__ q_b,
               const float* __restrict__ o_w, const float* __restrict__ o_b,
               const float* __restrict__ ln2_g, const float* __restrict__ ln2_b,
               float* __restrict__ out)
{
  __shared__ float s_x[64*68];
  __shared__ float s_q[64*68];
  const int tid = threadIdx.x;
  const size_t tb = (size_t)blockIdx.x * 64;

  for(int i = tid; i < 64*64; i += 256){
    int t = i >> 6, c = i & 63;
    s_x[t*68 + c] = xT[(tb + t)*64 + c];
  }
  __syncthreads();

  {
    const int r0 = (tid & 15) * 4, t0 = (tid >> 4) * 4;
    float4 b4 = *(const float4*)&q_b[r0];
    float4 acc[4];
    #pragma unroll
    for(int tt=0;tt<4;tt++) acc[tt] = b4;
    for(int c0=0;c0<64;c0+=4){
      float4 w0 = *(const float4*)&q_w[(r0+0)*64 + c0];
      float4 w1 = *(const float4*)&q_w[(r0+1)*64 + c0];
      float4 w2 = *(const float4*)&q_w[(r0+2)*64 + c0];
      float4 w3 = *(const float4*)&q_w[(r0+3)*64 + c0];
      #pragma unroll
      for(int tt=0;tt<4;tt++){
        float4 x4 = *(const float4*)&s_x[(t0+tt)*68 + c0];
        acc[tt].x = dp4(x4, w0, acc[tt].x);
        acc[tt].y = dp4(x4, w1, acc[tt].y);
        acc[tt].z = dp4(x4, w2, acc[tt].z);
        acc[tt].w = dp4(x4, w3, acc[tt].w);
      }
    }
    #pragma unroll
    for(int tt=0;tt<4;tt++)
      *(float4*)&s_q[(t0+tt)*68 + r0] = acc[tt];
  }
  __syncthreads();

  const int td = tid >> 2, h = tid & 3;
  const size_t idxg = tb + td;
  const int n  = (int)(idxg % NODES);
  const int bt = (int)(idxg / NODES);

  const float* qp = &s_q[td*68 + h*16];
  float4 q0 = *(const float4*)(qp+0);
  float4 q1 = *(const float4*)(qp+4);
  float4 q2 = *(const float4*)(qp+8);
  float4 q3 = *(const float4*)(qp+12);
  int rows[TOPK];
  #pragma unroll
  for(int k=0;k<TOPK;k++) rows[k] = bt*NODES + nbr[n*TOPK + k];
  __syncthreads();

  float sc[TOPK];
  #pragma unroll
  for(int k=0;k<TOPK;k++){
    const float* kr = &Kb[(size_t)rows[k]*64 + h*16];
    float4 k0 = *(const float4*)(kr+0);
    float4 k1 = *(const float4*)(kr+4);
    float4 k2 = *(const float4*)(kr+8);
    float4 k3 = *(const float4*)(kr+12);
    float s = dp4(q0,k0, dp4(q1,k1, dp4(q2,k2, dp4(q3,k3, 0.f))));
    sc[k] = s * 0.25f;
  }
  float mx = sc[0];
  #pragma unroll
  for(int k=1;k<TOPK;k++) mx = fmaxf(mx, sc[k]);
  float ssum = 0.f;
  #pragma unroll
  for(int k=0;k<TOPK;k++){ sc[k] = __expf(sc[k]-mx); ssum += sc[k]; }
  float inv = 1.f/ssum;
  float4 o0 = make_float4(0.f,0.f,0.f,0.f), o1 = o0, o2 = o0, o3 = o0;
  #pragma unroll
  for(int k=0;k<TOPK;k++){
    const float* vr = &Vb[(size_t)rows[k]*64 + h*16];
    float p = sc[k]*inv;
    o0 = f4fma(p, *(const float4*)(vr+0),  o0);
    o1 = f4fma(p, *(const float4*)(vr+4),  o1);
    o2 = f4fma(p, *(const float4*)(vr+8),  o2);
    o3 = f4fma(p, *(const float4*)(vr+12), o3);
  }
  {
    float* op = &s_q[td*68 + h*16];
    *(float4*)(op+0)  = o0;
    *(float4*)(op+4)  = o1;
    *(float4*)(op+8)  = o2;
    *(float4*)(op+12) = o3;
  }
  __syncthreads();

  float4 ores[4];
  const int r0 = (tid & 15) * 4, t0 = (tid >> 4) * 4;
  {
    float4 b4 = *(const float4*)&o_b[r0];
    float4 acc[4];
    #pragma unroll
    for(int tt=0;tt<4;tt++) acc[tt] = b4;
    for(int c0=0;c0<64;c0+=4){
      float4 w0 = *(const float4*)&o_w[(r0+0)*64 + c0];
      float4 w1 = *(const float4*)&o_w[(r0+1)*64 + c0];
      float4 w2 = *(const float4*)&o_w[(r0+2)*64 + c0];
      float4 w3 = *(const float4*)&o_w[(r0+3)*64 + c0];
      #pragma unroll
      for(int tt=0;tt<4;tt++){
        float4 g4 = *(const float4*)&s_q[(t0+tt)*68 + c0];
        acc[tt].x = dp4(g4, w0, acc[tt].x);
        acc[tt].y = dp4(g4, w1, acc[tt].y);
        acc[tt].z = dp4(g4, w2, acc[tt].z);
        acc[tt].w = dp4(g4, w3, acc[tt].w);
      }
    }
    #pragma unroll
    for(int tt=0;tt<4;tt++){
      float g = gate[tb + t0 + tt];
      float4 xv = *(const float4*)&s_x[(t0+tt)*68 + r0];
      ores[tt].x = xv.x + g*(acc[tt].x - xv.x);
      ores[tt].y = xv.y + g*(acc[tt].y - xv.y);
      ores[tt].z = xv.z + g*(acc[tt].z - xv.z);
      ores[tt].w = xv.w + g*(acc[tt].w - xv.w);
    }
  }
  __syncthreads();
  #pragma unroll
  for(int tt=0;tt<4;tt++)
    *(float4*)&s_q[(t0+tt)*68 + r0] = ores[tt];
  __syncthreads();

  {
    const float* orow = &s_q[td*68 + h*16];
    float4 a0 = *(const float4*)(orow+0);
    float4 a1 = *(const float4*)(orow+4);
    float4 a2 = *(const float4*)(orow+8);
    float4 a3 = *(const float4*)(orow+12);
    float sum = (a0.x+a0.y+a0.z+a0.w) + (a1.x+a1.y+a1.z+a1.w)
              + (a2.x+a2.y+a2.z+a2.w) + (a3.x+a3.y+a3.z+a3.w);
    sum += __shfl_xor(sum, 1, 64);
    sum += __shfl_xor(sum, 2, 64);
    float mean = sum * (1.f/64.f);
    a0.x-=mean; a0.y-=mean; a0.z-=mean; a0.w-=mean;
    a1.x-=mean; a1.y-=mean; a1.z-=mean; a1.w-=mean;
    a2.x-=mean; a2.y-=mean; a2.z-=mean; a2.w-=mean;
    a3.x-=mean; a3.y-=mean; a3.z-=mean; a3.w-=mean;
    float sq = (a0.x*a0.x+a0.y*a0.y+a0.z*a0.z+a0.w*a0.w)
             + (a1.x*a1.x+a1.y*a1.y+a1.z*a1.z+a1.w*a1.w)
             + (a2.x*a2.x+a2.y*a2.y+a2.z*a2.z+a2.w*a2.w)
             + (a3.x*a3.x+a3.y*a3.y+a3.z*a3.z+a3.w*a3.w);
    sq += __shfl_xor(sq, 1, 64);
    sq += __shfl_xor(sq, 2, 64);
    float rstd = rsqrtf(sq*(1.f/64.f) + EPS);
    float4 g0 = *(const float4*)&ln2_g[h*16+0];
    float4 g1 = *(const float4*)&ln2_g[h*16+4];
    float4 g2 = *(const float4*)&ln2_g[h*16+8];
    float4 g3 = *(const float4*)&ln2_g[h*16+12];
    float4 bb0 = *(const float4*)&ln2_b[h*16+0];
    float4 bb1 = *(const float4*)&ln2_b[h*16+4];
    float4 bb2 = *(const float4*)&ln2_b[h*16+8];
    float4 bb3 = *(const float4*)&ln2_b[h*16+12];
    float* po = &out[idxg*64 + h*16];
    float4 r;
    r.x=a0.x*rstd*g0.x+bb0.x; r.y=a0.y*rstd*g0.y+bb0.y; r.z=a0.z*rstd*g0.z+bb0.z; r.w=a0.w*rstd*g0.w+bb0.w;
    *(float4*)(po+0) = r;
    r.x=a1.x*rstd*g1.x+bb1.x; r.y=a1.y*rstd*g1.y+bb1.y; r.z=a1.z*rstd*g1.z+bb1.z; r.w=a1.w*rstd*g1.w+bb1.w;
    *(float4*)(po+4) = r;
    r.x=a2.x*rstd*g2.x+bb2.x; r.y=a2.y*rstd*g2.y+bb2.y; r.z=a2.z*rstd*g2.z+bb2.z; r.w=a2.w*rstd*g2.w+bb2.w;
    *(float4*)(po+8) = r;
    r.x=a3.x*rstd*g3.x+bb3.x; r.y=a3.y*rstd*g3.y+bb3.y; r.z=a3.z*rstd*g3.z+bb3.z; r.w=a3.w*rstd*g3.w+bb3.w;
    *(float4*)(po+12) = r;
  }
}

// ---------------- Fallback fused attn (used only if ws too small) ----------------
__global__ __launch_bounds__(64)
void opt_attn(const float* __restrict__ xT, const int* __restrict__ nbr,
              const float* __restrict__ q_w, const float* __restrict__ q_b,
              const float* __restrict__ k_w, const float* __restrict__ k_b,
              const float* __restrict__ v_w, const float* __restrict__ v_b,
              const float* __restrict__ o_w, const float* __restrict__ o_b,
              const float* __restrict__ g1_w, const float* __restrict__ g1_b,
              const float* __restrict__ g2_w, const float* __restrict__ g2_b,
              const float* __restrict__ ln2_g, const float* __restrict__ ln2_b,
              float* __restrict__ out)
{
  const int idx = blockIdx.x;
  const int n   = idx % NODES;
  const int bt  = idx / NODES;
  const int j   = threadIdx.x;

  __shared__ float s_x[64];
  __shared__ float s_nb[TOPK][64];
  __shared__ float s_og[64];
  __shared__ float s_gate;

  float xv = xT[(size_t)idx*64 + j];
  s_x[j] = xv;
  const int base = bt * NODES;
  #pragma unroll
  for(int k=0;k<TOPK;k++){
    int nb2 = nbr[n*TOPK + k];
    s_nb[k][j] = xT[(size_t)(base + nb2)*64 + j];
  }
  __syncthreads();

  float Qj = dot64(s_x, q_w + j*64, q_b[j]);

  float sc[TOPK], vv[TOPK];
  #pragma unroll
  for(int k=0;k<TOPK;k++){
    float Kk = dot64(s_nb[k], k_w + j*64, k_b[j]);
    vv[k]    = dot64(s_nb[k], v_w + j*64, v_b[j]);
    sc[k]    = groupSum16(Qj * Kk) * 0.25f;
  }
  float m = sc[0];
  #pragma unroll
  for(int k=1;k<TOPK;k++) m = fmaxf(m, sc[k]);
  float ssum = 0.f;
  #pragma unroll
  for(int k=0;k<TOPK;k++){ sc[k] = __expf(sc[k]-m); ssum += sc[k]; }
  float inv = 1.f/ssum;
  float og = 0.f;
  #pragma unroll
  for(int k=0;k<TOPK;k++) og = fmaf(sc[k]*inv, vv[k], og);
  s_og[j] = og;
  __syncthreads();

  float xg = dot64(s_og, o_w + j*64, o_b[j]);

  if(j < 16){
    float u = dot64(s_x, g1_w + j*64, g1_b[j]);
    u = 0.5f * u * (1.f + erff(u * 0.70710678118654752f));
    float contrib = groupSum16(u * g2_w[j]);
    if(j == 0) s_gate = 1.f / (1.f + __expf(-(contrib + g2_b[0])));
  }
  __syncthreads();

  float gg = s_gate;
  float o  = xv + gg * (xg - xv);

  float mm  = waveSum64(o) * (1.f/64.f);
  float c   = o - mm;
  float var = waveSum64(c*c) * (1.f/64.f);
  out[(size_t)idx*64 + j] = c * rsqrtf(var + EPS) * ln2_g[j] + ln2_b[j];
}

extern "C" void kernel_launch(void* const* d_in, const int* in_sizes, int n_in,
                              void* d_out, int out_size, void* d_ws, size_t ws_size,
                              hipStream_t stream)
{
  const float* x      = (const float*)d_in[0];
  const int*   nbr    = (const int*  )d_in[1];
  const float* ln1_g  = (const float*)d_in[2];
  const float* ln1_b  = (const float*)d_in[3];
  const float* in_w   = (const float*)d_in[4];
  const float* conv_w = (const float*)d_in[5];
  const float* conv_b = (const float*)d_in[6];
  const float* xp_w   = (const float*)d_in[7];
  const float* dt_w   = (const float*)d_in[8];
  const float* dt_b   = (const float*)d_in[9];
  const float* A_log  = (const float*)d_in[10];
  const float* Dss    = (const float*)d_in[11];
  const float* out_w  = (const float*)d_in[12];
  const float* q_w    = (const float*)d_in[13];
  const float* q_b    = (const float*)d_in[14];
  const float* k_w    = (const float*)d_in[15];
  const float* k_b    = (const float*)d_in[16];
  const float* v_w    = (const float*)d_in[17];
  const float* v_b    = (const float*)d_in[18];
  const float* o_w    = (const float*)d_in[19];
  const float* o_b    = (const float*)d_in[20];
  const float* g1_w   = (const float*)d_in[21];
  const float* g1_b   = (const float*)d_in[22];
  const float* g2_w   = (const float*)d_in[23];
  const float* g2_b   = (const float*)d_in[24];
  const float* ln2_g  = (const float*)d_in[25];
  const float* ln2_b  = (const float*)d_in[26];

  float* xT   = (float*)d_ws;                 // 42.6 MB
  float* Kb   = xT + NTOK*64;                 // +42.6 MB
  float* Vb   = Kb + NTOK*64;                 // +42.6 MB
  float* gg   = Vb + NTOK*64;                 // +0.67 MB
  float* outp = (float*)d_out;

  const size_t need = (NTOK*64*3 + NTOK) * sizeof(float);   // ~128.5 MB (proven R2-R8)

  (void)hipFuncSetAttribute(reinterpret_cast<const void*>(opt_mamba),
                            hipFuncAttributeMaxDynamicSharedMemorySize, SMEM_BYTES);

  opt_mamba<<<dim3(B_SZ*NODES), dim3(512), SMEM_BYTES, stream>>>(
      x, ln1_g, ln1_b, in_w, conv_w, conv_b, xp_w, dt_w, dt_b, A_log, Dss, out_w, xT);

  if(ws_size >= need){
    opt_proj<<<dim3((unsigned)(NTOK/64)), dim3(256), 0, stream>>>(
        xT, k_w, k_b, v_w, v_b, g1_w, g1_b, g2_w, g2_b, Kb, Vb, gg);
    opt_attn3<<<dim3((unsigned)(NTOK/64)), dim3(256), 0, stream>>>(
        xT, Kb, Vb, gg, nbr, q_w, q_b, o_w, o_b, ln2_g, ln2_b, outp);
  } else {
    opt_attn<<<dim3((unsigned)NTOK), dim3(64), 0, stream>>>(
        xT, nbr, q_w, q_b, k_w, k_b, v_w, v_b, o_w, o_b,
        g1_w, g1_b, g2_w, g2_b, ln2_g, ln2_b, outp);
  }
}

// Round 11
// 1392.105 us; speedup vs baseline: 1.3727x; 1.3727x over previous
//
#include <hip/hip_runtime.h>
#include <math.h>

#define NODES   325
#define TOPK    8
#define B_SZ    8
#define T_LEN   64
#define EPS     1e-5f
#define NTOK    ((size_t)B_SZ * T_LEN * NODES)   /* 166,400 */

/* ---- LDS layout for opt_mamba (R3-measured-801 layout, verbatim) ----
   s_h   [64][64]   LN output            4096
   s_xc  [64][132]  xi -> xc -> y -> u   8448
   s_dbl [64][40]   x_proj output        2560
   s_dtv [64][128]  precomputed dt       8192
   sW    [8704]     in_wT halves / out_wT
   total 32000 floats = 128000 B -> 1 block/CU, 8 waves (512 thr).
   Multi-block residency is INFEASIBLE with staged weights: usable
   dynamic-LDS pool measured ~128 KB/CU (61.4 KB->2blk [R5], 68.6/78.8
   KB->1blk [R9/R4]); staged weights need >=69 KB. */
#define WPAD    132
#define OWPAD   68
#define XCPAD   132
#define DBLPAD  40
#define OFF_H   0
#define OFF_XC  4096
#define OFF_DBL 12544
#define OFF_DTV 15104
#define OFF_W   23296
#define SMEM_BYTES ((23296+8704)*4)

__device__ __forceinline__ float waveSum64(float v){
  #pragma unroll
  for(int m=1;m<64;m<<=1) v += __shfl_xor(v, m, 64);
  return v;
}
__device__ __forceinline__ float groupSum16(float v){
  v += __shfl_xor(v, 1, 64);
  v += __shfl_xor(v, 2, 64);
  v += __shfl_xor(v, 4, 64);
  v += __shfl_xor(v, 8, 64);
  return v;
}
__device__ __forceinline__ float dot64(const float* __restrict__ s,
                                       const float* __restrict__ w, float acc){
  #pragma unroll
  for(int q=0;q<64;q++) acc = fmaf(s[q], w[q], acc);
  return acc;
}
__device__ __forceinline__ float4 f4fma(float s, float4 a, float4 acc){
  acc.x = fmaf(s, a.x, acc.x);
  acc.y = fmaf(s, a.y, acc.y);
  acc.z = fmaf(s, a.z, acc.z);
  acc.w = fmaf(s, a.w, acc.w);
  return acc;
}
__device__ __forceinline__ float dp4(float4 a, float4 b, float acc){
  acc = fmaf(a.x, b.x, acc);
  acc = fmaf(a.y, b.y, acc);
  acc = fmaf(a.z, b.z, acc);
  acc = fmaf(a.w, b.w, acc);
  return acc;
}

// ---------------- Mamba R10: R3-measured-801 kernel; scan -> 512 threads ----------------
__global__ __launch_bounds__(512)
void opt_mamba(const float* __restrict__ x,
               const float* __restrict__ ln1_g, const float* __restrict__ ln1_b,
               const float* __restrict__ in_w,
               const float* __restrict__ conv_w, const float* __restrict__ conv_b,
               const float* __restrict__ xp_w,
               const float* __restrict__ dt_w, const float* __restrict__ dt_b,
               const float* __restrict__ A_log, const float* __restrict__ Dss,
               const float* __restrict__ out_w,
               float* __restrict__ xT)
{
  extern __shared__ float sm[];
  float* s_h   = sm + OFF_H;
  float* s_xc  = sm + OFF_XC;
  float* s_dbl = sm + OFF_DBL;
  float* s_dtv = sm + OFF_DTV;
  float* sW    = sm + OFF_W;

  const int bn   = blockIdx.x;
  const int b    = bn / NODES;
  const int n    = bn % NODES;
  const int tid  = threadIdx.x;
  const int lane = tid & 63;
  const int wv   = tid >> 6;

  const int r0 = (tid & 31) * 4;     // channel rows r0..r0+3 (phases 2/4a/6)
  const int t0 = (tid >> 5) * 4;     // tokens t0..t0+3

  // ---- Phase 1: stage in_wT lo (xi rows) + LayerNorm all 64 tokens
  for(int idx = tid; idx < 128*64; idx += 512){
    int r = idx >> 6, c = idx & 63;
    sW[c*WPAD + r] = in_w[idx];
  }
  {
    const float g_ln = ln1_g[lane], b_ln = ln1_b[lane];
    #pragma unroll
    for(int i=0;i<8;i++){
      int t = wv*8 + i;
      size_t tok = (size_t)(b*T_LEN + t)*NODES + n;
      float v   = x[tok*64 + lane];
      float m   = waveSum64(v) * (1.f/64.f);
      float c   = v - m;
      float var = waveSum64(c*c) * (1.f/64.f);
      s_h[t*64 + lane] = c * rsqrtf(var + EPS) * g_ln + b_ln;
    }
  }
  __syncthreads();

  // ---- Phase 2: xi = h @ in_w[0:128].T  (4 rows x 4 tokens per thread)
  {
    float4 acc[4];
    #pragma unroll
    for(int tt=0;tt<4;tt++) acc[tt] = make_float4(0.f,0.f,0.f,0.f);
    for(int c0=0;c0<64;c0+=4){
      float4 w0 = *(const float4*)&sW[(c0+0)*WPAD + r0];
      float4 w1 = *(const float4*)&sW[(c0+1)*WPAD + r0];
      float4 w2 = *(const float4*)&sW[(c0+2)*WPAD + r0];
      float4 w3 = *(const float4*)&sW[(c0+3)*WPAD + r0];
      #pragma unroll
      for(int tt=0;tt<4;tt++){
        float4 h4 = *(const float4*)&s_h[(t0+tt)*64 + c0];
        acc[tt] = f4fma(h4.x, w0, acc[tt]);
        acc[tt] = f4fma(h4.y, w1, acc[tt]);
        acc[tt] = f4fma(h4.z, w2, acc[tt]);
        acc[tt] = f4fma(h4.w, w3, acc[tt]);
      }
    }
    #pragma unroll
    for(int tt=0;tt<4;tt++)
      *(float4*)&s_xc[(t0+tt)*XCPAD + r0] = acc[tt];
  }
  __syncthreads();

  // ---- Phase 3: causal conv (window 4) + silu, 4 token-quarters; restage W hi
  {
    const int dd = tid & 127, tg = tid >> 7;   // quarter tg: tokens 16tg..16tg+15
    float p3 = 0.f, p2 = 0.f, p1 = 0.f;
    if(tg){
      int tq = tg*16;
      p3 = s_xc[(tq-3)*XCPAD + dd];
      p2 = s_xc[(tq-2)*XCPAD + dd];
      p1 = s_xc[(tq-1)*XCPAD + dd];
    }
    __syncthreads();
    const float cw0 = conv_w[dd*4+0], cw1 = conv_w[dd*4+1];
    const float cw2 = conv_w[dd*4+2], cw3 = conv_w[dd*4+3];
    const float cb  = conv_b[dd];
    for(int t=tg*16; t<tg*16+16; t++){
      float xi = s_xc[t*XCPAD + dd];
      float v  = cb + cw0*p3 + cw1*p2 + cw2*p1 + cw3*xi;
      p3 = p2; p2 = p1; p1 = xi;
      s_xc[t*XCPAD + dd] = v / (1.f + __expf(-v));
    }
    for(int idx = tid; idx < 128*64; idx += 512){
      int r = idx >> 6, c = idx & 63;
      sW[c*WPAD + r] = in_w[128*64 + idx];
    }
  }
  __syncthreads();

  // ---- Phase 4a: z = h @ in_w[128:256].T -> registers
  float4 zr[4];
  {
    #pragma unroll
    for(int tt=0;tt<4;tt++) zr[tt] = make_float4(0.f,0.f,0.f,0.f);
    for(int c0=0;c0<64;c0+=4){
      float4 w0 = *(const float4*)&sW[(c0+0)*WPAD + r0];
      float4 w1 = *(const float4*)&sW[(c0+1)*WPAD + r0];
      float4 w2 = *(const float4*)&sW[(c0+2)*WPAD + r0];
      float4 w3 = *(const float4*)&sW[(c0+3)*WPAD + r0];
      #pragma unroll
      for(int tt=0;tt<4;tt++){
        float4 h4 = *(const float4*)&s_h[(t0+tt)*64 + c0];
        zr[tt] = f4fma(h4.x, w0, zr[tt]);
        zr[tt] = f4fma(h4.y, w1, zr[tt]);
        zr[tt] = f4fma(h4.z, w2, zr[tt]);
        zr[tt] = f4fma(h4.w, w3, zr[tt]);
      }
    }
  }

  // ---- Phase 4b: dbl = xc @ x_proj.T (36 rows over 8 wave-groups)
  {
    const int td = tid & 63, rg = tid >> 6;
    const int base = rg*5;                     // rows base..base+4, guard <36
    float dacc[5];
    #pragma unroll
    for(int i=0;i<5;i++) dacc[i] = 0.f;
    for(int c0=0;c0<128;c0+=4){
      float4 xc4 = *(const float4*)&s_xc[td*XCPAD + c0];
      #pragma unroll
      for(int i=0;i<5;i++){
        if(base+i < 36){
          float4 w4 = *(const float4*)&xp_w[(base+i)*128 + c0];
          dacc[i] = dp4(xc4, w4, dacc[i]);
        }
      }
    }
    #pragma unroll
    for(int i=0;i<5;i++)
      if(base+i < 36) s_dbl[td*DBLPAD + base + i] = dacc[i];
  }
  __syncthreads();

  // ---- Phase 4c: precompute dt (softplus) fully parallel (R3-proven)
  {
    const int d = tid & 127, tq = tid >> 7;
    const float dtw0 = dt_w[d*4+0], dtw1 = dt_w[d*4+1];
    const float dtw2 = dt_w[d*4+2], dtw3 = dt_w[d*4+3];
    const float dtb  = dt_b[d];
    #pragma unroll
    for(int j=0;j<16;j++){
      int t = tq + j*4;
      const float* db = &s_dbl[t*DBLPAD];
      float dtv = dtb;
      dtv = fmaf(db[0], dtw0, dtv);
      dtv = fmaf(db[1], dtw1, dtv);
      dtv = fmaf(db[2], dtw2, dtv);
      dtv = fmaf(db[3], dtw3, dtv);
      dtv = fmaxf(dtv, 0.f) + log1pf(__expf(-fabsf(dtv)));
      s_dtv[t*128 + d] = dtv;
    }
  }
  __syncthreads();

  // ---- Phase 5 (the ONE delta vs R3): scan with ALL 512 threads,
  //      d = tid>>2, s-quartet = tid&3, dtv read from s_dtv (no softplus
  //      on the serial chain), 2-shuffle y-reduce.
  {
    const int d  = tid >> 2;
    const int sq = tid & 3;
    float A_d[4], hs[4];
    #pragma unroll
    for(int i=0;i<4;i++){ A_d[i] = -__expf(A_log[d*16 + sq*4 + i]); hs[i] = 0.f; }
    const float Dd = Dss[d];
    for(int t=0;t<T_LEN;t++){
      const float* db = &s_dbl[t*DBLPAD];
      float dtv = s_dtv[t*128 + d];
      float xc  = s_xc[t*XCPAD + d];
      float dx  = dtv * xc;
      float4 Bv = *(const float4*)&db[4  + sq*4];
      float4 Cv = *(const float4*)&db[20 + sq*4];
      float yp = 0.f;
      hs[0] = fmaf(dx, Bv.x, hs[0]*__expf(dtv*A_d[0])); yp = fmaf(hs[0], Cv.x, yp);
      hs[1] = fmaf(dx, Bv.y, hs[1]*__expf(dtv*A_d[1])); yp = fmaf(hs[1], Cv.y, yp);
      hs[2] = fmaf(dx, Bv.z, hs[2]*__expf(dtv*A_d[2])); yp = fmaf(hs[2], Cv.z, yp);
      hs[3] = fmaf(dx, Bv.w, hs[3]*__expf(dtv*A_d[3])); yp = fmaf(hs[3], Cv.w, yp);
      yp += __shfl_xor(yp, 1, 64);
      yp += __shfl_xor(yp, 2, 64);
      if(sq == 0) s_xc[t*XCPAD + d] = yp + Dd*xc;
    }
  }
  __syncthreads();

  // ---- Phase 6: u = y * silu(z); stage out_wT
  {
    #pragma unroll
    for(int tt=0;tt<4;tt++){
      float4 y4 = *(const float4*)&s_xc[(t0+tt)*XCPAD + r0];
      float4 z4 = zr[tt];
      float4 u;
      u.x = y4.x * (z4.x / (1.f + __expf(-z4.x)));
      u.y = y4.y * (z4.y / (1.f + __expf(-z4.y)));
      u.z = y4.z * (z4.z / (1.f + __expf(-z4.z)));
      u.w = y4.w * (z4.w / (1.f + __expf(-z4.w)));
      *(float4*)&s_xc[(t0+tt)*XCPAD + r0] = u;
    }
    for(int idx = tid; idx < 64*128; idx += 512){
      int j = idx >> 7, c = idx & 127;
      sW[c*OWPAD + j] = out_w[idx];
    }
  }
  __syncthreads();

  // ---- Phase 7: out = u @ out_w.T + x residual -> xT (4 dims x 2 tokens)
  {
    const int j0  = (tid & 15) * 4;
    const int t0o = (tid >> 4) * 2;
    float4 oacc[2];
    #pragma unroll
    for(int tt=0;tt<2;tt++) oacc[tt] = make_float4(0.f,0.f,0.f,0.f);
    for(int c0=0;c0<128;c0+=4){
      float4 w0 = *(const float4*)&sW[(c0+0)*OWPAD + j0];
      float4 w1 = *(const float4*)&sW[(c0+1)*OWPAD + j0];
      float4 w2 = *(const float4*)&sW[(c0+2)*OWPAD + j0];
      float4 w3 = *(const float4*)&sW[(c0+3)*OWPAD + j0];
      #pragma unroll
      for(int tt=0;tt<2;tt++){
        float4 u4 = *(const float4*)&s_xc[(t0o+tt)*XCPAD + c0];
        oacc[tt] = f4fma(u4.x, w0, oacc[tt]);
        oacc[tt] = f4fma(u4.y, w1, oacc[tt]);
        oacc[tt] = f4fma(u4.z, w2, oacc[tt]);
        oacc[tt] = f4fma(u4.w, w3, oacc[tt]);
      }
    }
    #pragma unroll
    for(int tt=0;tt<2;tt++){
      int t = t0o + tt;
      size_t tok = (size_t)(b*T_LEN + t)*NODES + n;
      float4 xv = *(const float4*)&x[tok*64 + j0];
      float4 o;
      o.x = xv.x + oacc[tt].x;
      o.y = xv.y + oacc[tt].y;
      o.z = xv.z + oacc[tt].z;
      o.w = xv.w + oacc[tt].w;
      *(float4*)&xT[tok*64 + j0] = o;
    }
  }
}

// ---------------- K/V + gate projection (R3-validated, unchanged) ----------------
__global__ __launch_bounds__(256)
void opt_proj(const float* __restrict__ xT,
              const float* __restrict__ k_w, const float* __restrict__ k_b,
              const float* __restrict__ v_w, const float* __restrict__ v_b,
              const float* __restrict__ g1_w, const float* __restrict__ g1_b,
              const float* __restrict__ g2_w, const float* __restrict__ g2_b,
              float* __restrict__ Kb, float* __restrict__ Vb,
              float* __restrict__ gate)
{
  __shared__ float s_x[64*68];
  const int tid = threadIdx.x;
  const size_t tb = (size_t)blockIdx.x * 64;

  for(int i = tid; i < 64*64; i += 256){
    int t = i >> 6, c = i & 63;
    s_x[t*68 + c] = xT[(tb + t)*64 + c];
  }
  __syncthreads();

  const int r0 = (tid & 15) * 4;
  const int t0 = (tid >> 4) * 4;

  {
    float4 b4 = *(const float4*)&k_b[r0];
    float4 acc[4];
    #pragma unroll
    for(int tt=0;tt<4;tt++) acc[tt] = b4;
    for(int c0=0;c0<64;c0+=4){
      float4 w0 = *(const float4*)&k_w[(r0+0)*64 + c0];
      float4 w1 = *(const float4*)&k_w[(r0+1)*64 + c0];
      float4 w2 = *(const float4*)&k_w[(r0+2)*64 + c0];
      float4 w3 = *(const float4*)&k_w[(r0+3)*64 + c0];
      #pragma unroll
      for(int tt=0;tt<4;tt++){
        float4 x4 = *(const float4*)&s_x[(t0+tt)*68 + c0];
        acc[tt].x = dp4(x4, w0, acc[tt].x);
        acc[tt].y = dp4(x4, w1, acc[tt].y);
        acc[tt].z = dp4(x4, w2, acc[tt].z);
        acc[tt].w = dp4(x4, w3, acc[tt].w);
      }
    }
    #pragma unroll
    for(int tt=0;tt<4;tt++)
      *(float4*)&Kb[(tb + t0 + tt)*64 + r0] = acc[tt];
  }

  {
    float4 b4 = *(const float4*)&v_b[r0];
    float4 acc[4];
    #pragma unroll
    for(int tt=0;tt<4;tt++) acc[tt] = b4;
    for(int c0=0;c0<64;c0+=4){
      float4 w0 = *(const float4*)&v_w[(r0+0)*64 + c0];
      float4 w1 = *(const float4*)&v_w[(r0+1)*64 + c0];
      float4 w2 = *(const float4*)&v_w[(r0+2)*64 + c0];
      float4 w3 = *(const float4*)&v_w[(r0+3)*64 + c0];
      #pragma unroll
      for(int tt=0;tt<4;tt++){
        float4 x4 = *(const float4*)&s_x[(t0+tt)*68 + c0];
        acc[tt].x = dp4(x4, w0, acc[tt].x);
        acc[tt].y = dp4(x4, w1, acc[tt].y);
        acc[tt].z = dp4(x4, w2, acc[tt].z);
        acc[tt].w = dp4(x4, w3, acc[tt].w);
      }
    }
    #pragma unroll
    for(int tt=0;tt<4;tt++)
      *(float4*)&Vb[(tb + t0 + tt)*64 + r0] = acc[tt];
  }

  {
    const int td = tid >> 2;
    const int sr = (tid & 3) * 4;
    float partial = 0.f;
    #pragma unroll
    for(int i=0;i<4;i++){
      int r = sr + i;
      float u = dot64(&s_x[td*68], g1_w + r*64, g1_b[r]);
      u = 0.5f * u * (1.f + erff(u * 0.70710678118654752f));
      partial = fmaf(u, g2_w[r], partial);
    }
    partial += __shfl_xor(partial, 1, 64);
    partial += __shfl_xor(partial, 2, 64);
    if((tid & 3) == 0)
      gate[tb + td] = 1.f / (1.f + __expf(-(partial + g2_b[0])));
  }
}

// ---------------- Tile attention (R3-validated, unchanged) ----------------
__global__ __launch_bounds__(256)
void opt_attn3(const float* __restrict__ xT,
               const float* __restrict__ Kb, const float* __restrict__ Vb,
               const float* __restrict__ gate, const int* __restrict__ nbr,
               const float* __restrict__ q_w, const float* __restrict__ q_b,
               const float* __restrict__ o_w, const float* __restrict__ o_b,
               const float* __restrict__ ln2_g, const float* __restrict__ ln2_b,
               float* __restrict__ out)
{
  __shared__ float s_x[64*68];
  __shared__ float s_q[64*68];
  const int tid = threadIdx.x;
  const size_t tb = (size_t)blockIdx.x * 64;

  for(int i = tid; i < 64*64; i += 256){
    int t = i >> 6, c = i & 63;
    s_x[t*68 + c] = xT[(tb + t)*64 + c];
  }
  __syncthreads();

  {
    const int r0 = (tid & 15) * 4, t0 = (tid >> 4) * 4;
    float4 b4 = *(const float4*)&q_b[r0];
    float4 acc[4];
    #pragma unroll
    for(int tt=0;tt<4;tt++) acc[tt] = b4;
    for(int c0=0;c0<64;c0+=4){
      float4 w0 = *(const float4*)&q_w[(r0+0)*64 + c0];
      float4 w1 = *(const float4*)&q_w[(r0+1)*64 + c0];
      float4 w2 = *(const float4*)&q_w[(r0+2)*64 + c0];
      float4 w3 = *(const float4*)&q_w[(r0+3)*64 + c0];
      #pragma unroll
      for(int tt=0;tt<4;tt++){
        float4 x4 = *(const float4*)&s_x[(t0+tt)*68 + c0];
        acc[tt].x = dp4(x4, w0, acc[tt].x);
        acc[tt].y = dp4(x4, w1, acc[tt].y);
        acc[tt].z = dp4(x4, w2, acc[tt].z);
        acc[tt].w = dp4(x4, w3, acc[tt].w);
      }
    }
    #pragma unroll
    for(int tt=0;tt<4;tt++)
      *(float4*)&s_q[(t0+tt)*68 + r0] = acc[tt];
  }
  __syncthreads();

  const int td = tid >> 2, h = tid & 3;
  const size_t idxg = tb + td;
  const int n  = (int)(idxg % NODES);
  const int bt = (int)(idxg / NODES);

  const float* qp = &s_q[td*68 + h*16];
  float4 q0 = *(const float4*)(qp+0);
  float4 q1 = *(const float4*)(qp+4);
  float4 q2 = *(const float4*)(qp+8);
  float4 q3 = *(const float4*)(qp+12);
  int rows[TOPK];
  #pragma unroll
  for(int k=0;k<TOPK;k++) rows[k] = bt*NODES + nbr[n*TOPK + k];
  __syncthreads();

  float sc[TOPK];
  #pragma unroll
  for(int k=0;k<TOPK;k++){
    const float* kr = &Kb[(size_t)rows[k]*64 + h*16];
    float4 k0 = *(const float4*)(kr+0);
    float4 k1 = *(const float4*)(kr+4);
    float4 k2 = *(const float4*)(kr+8);
    float4 k3 = *(const float4*)(kr+12);
    float s = dp4(q0,k0, dp4(q1,k1, dp4(q2,k2, dp4(q3,k3, 0.f))));
    sc[k] = s * 0.25f;
  }
  float mx = sc[0];
  #pragma unroll
  for(int k=1;k<TOPK;k++) mx = fmaxf(mx, sc[k]);
  float ssum = 0.f;
  #pragma unroll
  for(int k=0;k<TOPK;k++){ sc[k] = __expf(sc[k]-mx); ssum += sc[k]; }
  float inv = 1.f/ssum;
  float4 o0 = make_float4(0.f,0.f,0.f,0.f), o1 = o0, o2 = o0, o3 = o0;
  #pragma unroll
  for(int k=0;k<TOPK;k++){
    const float* vr = &Vb[(size_t)rows[k]*64 + h*16];
    float p = sc[k]*inv;
    o0 = f4fma(p, *(const float4*)(vr+0),  o0);
    o1 = f4fma(p, *(const float4*)(vr+4),  o1);
    o2 = f4fma(p, *(const float4*)(vr+8),  o2);
    o3 = f4fma(p, *(const float4*)(vr+12), o3);
  }
  {
    float* op = &s_q[td*68 + h*16];
    *(float4*)(op+0)  = o0;
    *(float4*)(op+4)  = o1;
    *(float4*)(op+8)  = o2;
    *(float4*)(op+12) = o3;
  }
  __syncthreads();

  float4 ores[4];
  const int r0 = (tid & 15) * 4, t0 = (tid >> 4) * 4;
  {
    float4 b4 = *(const float4*)&o_b[r0];
    float4 acc[4];
    #pragma unroll
    for(int tt=0;tt<4;tt++) acc[tt] = b4;
    for(int c0=0;c0<64;c0+=4){
      float4 w0 = *(const float4*)&o_w[(r0+0)*64 + c0];
      float4 w1 = *(const float4*)&o_w[(r0+1)*64 + c0];
      float4 w2 = *(const float4*)&o_w[(r0+2)*64 + c0];
      float4 w3 = *(const float4*)&o_w[(r0+3)*64 + c0];
      #pragma unroll
      for(int tt=0;tt<4;tt++){
        float4 g4 = *(const float4*)&s_q[(t0+tt)*68 + c0];
        acc[tt].x = dp4(g4, w0, acc[tt].x);
        acc[tt].y = dp4(g4, w1, acc[tt].y);
        acc[tt].z = dp4(g4, w2, acc[tt].z);
        acc[tt].w = dp4(g4, w3, acc[tt].w);
      }
    }
    #pragma unroll
    for(int tt=0;tt<4;tt++){
      float g = gate[tb + t0 + tt];
      float4 xv = *(const float4*)&s_x[(t0+tt)*68 + r0];
      ores[tt].x = xv.x + g*(acc[tt].x - xv.x);
      ores[tt].y = xv.y + g*(acc[tt].y - xv.y);
      ores[tt].z = xv.z + g*(acc[tt].z - xv.z);
      ores[tt].w = xv.w + g*(acc[tt].w - xv.w);
    }
  }
  __syncthreads();
  #pragma unroll
  for(int tt=0;tt<4;tt++)
    *(float4*)&s_q[(t0+tt)*68 + r0] = ores[tt];
  __syncthreads();

  {
    const float* orow = &s_q[td*68 + h*16];
    float4 a0 = *(const float4*)(orow+0);
    float4 a1 = *(const float4*)(orow+4);
    float4 a2 = *(const float4*)(orow+8);
    float4 a3 = *(const float4*)(orow+12);
    float sum = (a0.x+a0.y+a0.z+a0.w) + (a1.x+a1.y+a1.z+a1.w)
              + (a2.x+a2.y+a2.z+a2.w) + (a3.x+a3.y+a3.z+a3.w);
    sum += __shfl_xor(sum, 1, 64);
    sum += __shfl_xor(sum, 2, 64);
    float mean = sum * (1.f/64.f);
    a0.x-=mean; a0.y-=mean; a0.z-=mean; a0.w-=mean;
    a1.x-=mean; a1.y-=mean; a1.z-=mean; a1.w-=mean;
    a2.x-=mean; a2.y-=mean; a2.z-=mean; a2.w-=mean;
    a3.x-=mean; a3.y-=mean; a3.z-=mean; a3.w-=mean;
    float sq = (a0.x*a0.x+a0.y*a0.y+a0.z*a0.z+a0.w*a0.w)
             + (a1.x*a1.x+a1.y*a1.y+a1.z*a1.z+a1.w*a1.w)
             + (a2.x*a2.x+a2.y*a2.y+a2.z*a2.z+a2.w*a2.w)
             + (a3.x*a3.x+a3.y*a3.y+a3.z*a3.z+a3.w*a3.w);
    sq += __shfl_xor(sq, 1, 64);
    sq += __shfl_xor(sq, 2, 64);
    float rstd = rsqrtf(sq*(1.f/64.f) + EPS);
    float4 g0 = *(const float4*)&ln2_g[h*16+0];
    float4 g1 = *(const float4*)&ln2_g[h*16+4];
    float4 g2 = *(const float4*)&ln2_g[h*16+8];
    float4 g3 = *(const float4*)&ln2_g[h*16+12];
    float4 bb0 = *(const float4*)&ln2_b[h*16+0];
    float4 bb1 = *(const float4*)&ln2_b[h*16+4];
    float4 bb2 = *(const float4*)&ln2_b[h*16+8];
    float4 bb3 = *(const float4*)&ln2_b[h*16+12];
    float* po = &out[idxg*64 + h*16];
    float4 r;
    r.x=a0.x*rstd*g0.x+bb0.x; r.y=a0.y*rstd*g0.y+bb0.y; r.z=a0.z*rstd*g0.z+bb0.z; r.w=a0.w*rstd*g0.w+bb0.w;
    *(float4*)(po+0) = r;
    r.x=a1.x*rstd*g1.x+bb1.x; r.y=a1.y*rstd*g1.y+bb1.y; r.z=a1.z*rstd*g1.z+bb1.z; r.w=a1.w*rstd*g1.w+bb1.w;
    *(float4*)(po+4) = r;
    r.x=a2.x*rstd*g2.x+bb2.x; r.y=a2.y*rstd*g2.y+bb2.y; r.z=a2.z*rstd*g2.z+bb2.z; r.w=a2.w*rstd*g2.w+bb2.w;
    *(float4*)(po+8) = r;
    r.x=a3.x*rstd*g3.x+bb3.x; r.y=a3.y*rstd*g3.y+bb3.y; r.z=a3.z*rstd*g3.z+bb3.z; r.w=a3.w*rstd*g3.w+bb3.w;
    *(float4*)(po+12) = r;
  }
}

// ---------------- Fallback fused attn (used only if ws too small) ----------------
__global__ __launch_bounds__(64)
void opt_attn(const float* __restrict__ xT, const int* __restrict__ nbr,
              const float* __restrict__ q_w, const float* __restrict__ q_b,
              const float* __restrict__ k_w, const float* __restrict__ k_b,
              const float* __restrict__ v_w, const float* __restrict__ v_b,
              const float* __restrict__ o_w, const float* __restrict__ o_b,
              const float* __restrict__ g1_w, const float* __restrict__ g1_b,
              const float* __restrict__ g2_w, const float* __restrict__ g2_b,
              const float* __restrict__ ln2_g, const float* __restrict__ ln2_b,
              float* __restrict__ out)
{
  const int idx = blockIdx.x;
  const int n   = idx % NODES;
  const int bt  = idx / NODES;
  const int j   = threadIdx.x;

  __shared__ float s_x[64];
  __shared__ float s_nb[TOPK][64];
  __shared__ float s_og[64];
  __shared__ float s_gate;

  float xv = xT[(size_t)idx*64 + j];
  s_x[j] = xv;
  const int base = bt * NODES;
  #pragma unroll
  for(int k=0;k<TOPK;k++){
    int nb2 = nbr[n*TOPK + k];
    s_nb[k][j] = xT[(size_t)(base + nb2)*64 + j];
  }
  __syncthreads();

  float Qj = dot64(s_x, q_w + j*64, q_b[j]);

  float sc[TOPK], vv[TOPK];
  #pragma unroll
  for(int k=0;k<TOPK;k++){
    float Kk = dot64(s_nb[k], k_w + j*64, k_b[j]);
    vv[k]    = dot64(s_nb[k], v_w + j*64, v_b[j]);
    sc[k]    = groupSum16(Qj * Kk) * 0.25f;
  }
  float m = sc[0];
  #pragma unroll
  for(int k=1;k<TOPK;k++) m = fmaxf(m, sc[k]);
  float ssum = 0.f;
  #pragma unroll
  for(int k=0;k<TOPK;k++){ sc[k] = __expf(sc[k]-m); ssum += sc[k]; }
  float inv = 1.f/ssum;
  float og = 0.f;
  #pragma unroll
  for(int k=0;k<TOPK;k++) og = fmaf(sc[k]*inv, vv[k], og);
  s_og[j] = og;
  __syncthreads();

  float xg = dot64(s_og, o_w + j*64, o_b[j]);

  if(j < 16){
    float u = dot64(s_x, g1_w + j*64, g1_b[j]);
    u = 0.5f * u * (1.f + erff(u * 0.70710678118654752f));
    float contrib = groupSum16(u * g2_w[j]);
    if(j == 0) s_gate = 1.f / (1.f + __expf(-(contrib + g2_b[0])));
  }
  __syncthreads();

  float gg = s_gate;
  float o  = xv + gg * (xg - xv);

  float mm  = waveSum64(o) * (1.f/64.f);
  float c   = o - mm;
  float var = waveSum64(c*c) * (1.f/64.f);
  out[(size_t)idx*64 + j] = c * rsqrtf(var + EPS) * ln2_g[j] + ln2_b[j];
}

extern "C" void kernel_launch(void* const* d_in, const int* in_sizes, int n_in,
                              void* d_out, int out_size, void* d_ws, size_t ws_size,
                              hipStream_t stream)
{
  const float* x      = (const float*)d_in[0];
  const int*   nbr    = (const int*  )d_in[1];
  const float* ln1_g  = (const float*)d_in[2];
  const float* ln1_b  = (const float*)d_in[3];
  const float* in_w   = (const float*)d_in[4];
  const float* conv_w = (const float*)d_in[5];
  const float* conv_b = (const float*)d_in[6];
  const float* xp_w   = (const float*)d_in[7];
  const float* dt_w   = (const float*)d_in[8];
  const float* dt_b   = (const float*)d_in[9];
  const float* A_log  = (const float*)d_in[10];
  const float* Dss    = (const float*)d_in[11];
  const float* out_w  = (const float*)d_in[12];
  const float* q_w    = (const float*)d_in[13];
  const float* q_b    = (const float*)d_in[14];
  const float* k_w    = (const float*)d_in[15];
  const float* k_b    = (const float*)d_in[16];
  const float* v_w    = (const float*)d_in[17];
  const float* v_b    = (const float*)d_in[18];
  const float* o_w    = (const float*)d_in[19];
  const float* o_b    = (const float*)d_in[20];
  const float* g1_w   = (const float*)d_in[21];
  const float* g1_b   = (const float*)d_in[22];
  const float* g2_w   = (const float*)d_in[23];
  const float* g2_b   = (const float*)d_in[24];
  const float* ln2_g  = (const float*)d_in[25];
  const float* ln2_b  = (const float*)d_in[26];

  float* xT   = (float*)d_ws;                 // 42.6 MB
  float* Kb   = xT + NTOK*64;                 // +42.6 MB
  float* Vb   = Kb + NTOK*64;                 // +42.6 MB
  float* gg   = Vb + NTOK*64;                 // +0.67 MB
  float* outp = (float*)d_out;

  const size_t need = (NTOK*64*3 + NTOK) * sizeof(float);   // ~128.5 MB (proven R2-R9)

  (void)hipFuncSetAttribute(reinterpret_cast<const void*>(opt_mamba),
                            hipFuncAttributeMaxDynamicSharedMemorySize, SMEM_BYTES);

  opt_mamba<<<dim3(B_SZ*NODES), dim3(512), SMEM_BYTES, stream>>>(
      x, ln1_g, ln1_b, in_w, conv_w, conv_b, xp_w, dt_w, dt_b, A_log, Dss, out_w, xT);

  if(ws_size >= need){
    opt_proj<<<dim3((unsigned)(NTOK/64)), dim3(256), 0, stream>>>(
        xT, k_w, k_b, v_w, v_b, g1_w, g1_b, g2_w, g2_b, Kb, Vb, gg);
    opt_attn3<<<dim3((unsigned)(NTOK/64)), dim3(256), 0, stream>>>(
        xT, Kb, Vb, gg, nbr, q_w, q_b, o_w, o_b, ln2_g, ln2_b, outp);
  } else {
    opt_attn<<<dim3((unsigned)NTOK), dim3(64), 0, stream>>>(
        xT, nbr, q_w, q_b, k_w, k_b, v_w, v_b, o_w, o_b,
        g1_w, g1_b, g2_w, g2_b, ln2_g, ln2_b, outp);
  }
}